// Round 1
// baseline (157.677 us; speedup 1.0000x reference)
//
#include <hip/hip_runtime.h>

#define NJ 24
#define NF 7
#define FS 6

// parent of each joint; parents[i] < i, so sequential order is topological
__device__ constexpr int kParents[NJ] = {-1, 0, 0, 0, 1, 2, 3, 4, 5, 6, 7, 8,
                                          9, 9, 9, 12, 13, 14, 16, 17, 18, 19, 20, 21};

__global__ __launch_bounds__(256) void se1d_kernel(
    const float* __restrict__ x,
    const float* __restrict__ W1,
    const float* __restrict__ b1,
    const float* __restrict__ W2,
    const float* __restrict__ b2,
    float* __restrict__ out, int B)
{
    // Stage all weights in LDS once per block (~10 KB). Uniform-address LDS
    // reads broadcast across the wave (no bank conflicts).
    __shared__ float sW1[NJ * NF * NF];  // 1176
    __shared__ float sb1[NJ * NF];       // 168
    __shared__ float sW2[NJ * NF * FS];  // 1008
    __shared__ float sb2[NJ * FS];       // 144

    const int t = threadIdx.x;
    for (int i = t; i < NJ * NF * NF; i += 256) sW1[i] = W1[i];
    for (int i = t; i < NJ * NF;      i += 256) sb1[i] = b1[i];
    for (int i = t; i < NJ * NF * FS; i += 256) sW2[i] = W2[i];
    for (int i = t; i < NJ * FS;      i += 256) sb2[i] = b2[i];
    __syncthreads();

    const int b = blockIdx.x * 256 + t;
    if (b >= B) return;

    // Load this sample's 24 x-values: 96 B contiguous, 16B-aligned.
    float xr[NJ];
    const float4* xv = reinterpret_cast<const float4*>(x + (size_t)b * NJ);
    #pragma unroll
    for (int c = 0; c < NJ / 4; ++c) {
        float4 v = xv[c];
        xr[c * 4 + 0] = v.x; xr[c * 4 + 1] = v.y;
        xr[c * 4 + 2] = v.z; xr[c * 4 + 3] = v.w;
    }

    // Fully-unrolled joint chain: feats indices are all compile-time, so this
    // array lives in registers; liveness keeps only ~3 joint feats alive.
    float feats[NJ][FS];
    float* outp = out + (size_t)b * (NJ * FS);

    #pragma unroll
    for (int i = 0; i < NJ; ++i) {
        const int p = kParents[i];

        float inp[NF];
        inp[0] = xr[i];
        #pragma unroll
        for (int j = 0; j < FS; ++j) inp[1 + j] = (p < 0) ? 0.0f : feats[p][j];

        float h[NF];
        #pragma unroll
        for (int j = 0; j < NF; ++j) h[j] = sb1[i * NF + j];
        #pragma unroll
        for (int k = 0; k < NF; ++k) {
            const float a = inp[k];
            #pragma unroll
            for (int j = 0; j < NF; ++j)
                h[j] = fmaf(a, sW1[i * NF * NF + k * NF + j], h[j]);
        }
        #pragma unroll
        for (int j = 0; j < NF; ++j) h[j] = fmaxf(h[j], 0.0f);

        float f[FS];
        #pragma unroll
        for (int j = 0; j < FS; ++j) f[j] = sb2[i * FS + j];
        #pragma unroll
        for (int k = 0; k < NF; ++k) {
            const float a = h[k];
            #pragma unroll
            for (int j = 0; j < FS; ++j)
                f[j] = fmaf(a, sW2[i * NF * FS + k * FS + j], f[j]);
        }
        #pragma unroll
        for (int j = 0; j < FS; ++j) {
            f[j] = fmaxf(f[j], 0.0f);
            feats[i][j] = f[j];
        }

        // Write joint-pairs: 12 floats = 3 x float4, 16B-aligned
        // (b*576 + (i-1)*24 bytes, i odd -> 48-multiple).
        if (i & 1) {
            float4 v0 = make_float4(feats[i - 1][0], feats[i - 1][1],
                                    feats[i - 1][2], feats[i - 1][3]);
            float4 v1 = make_float4(feats[i - 1][4], feats[i - 1][5],
                                    f[0], f[1]);
            float4 v2 = make_float4(f[2], f[3], f[4], f[5]);
            float4* op = reinterpret_cast<float4*>(outp + (size_t)(i - 1) * FS);
            op[0] = v0; op[1] = v1; op[2] = v2;
        }
    }
}

extern "C" void kernel_launch(void* const* d_in, const int* in_sizes, int n_in,
                              void* d_out, int out_size, void* d_ws, size_t ws_size,
                              hipStream_t stream) {
    const float* x  = (const float*)d_in[0];
    const float* W1 = (const float*)d_in[1];
    const float* b1 = (const float*)d_in[2];
    const float* W2 = (const float*)d_in[3];
    const float* b2 = (const float*)d_in[4];
    float* out = (float*)d_out;
    const int B = in_sizes[0] / NJ;
    const int grid = (B + 255) / 256;
    hipLaunchKernelGGL(se1d_kernel, dim3(grid), dim3(256), 0, stream,
                       x, W1, b1, W2, b2, out, B);
}